// Round 2
// baseline (355.418 us; speedup 1.0000x reference)
//
#include <hip/hip_runtime.h>
#include <hip/hip_bf16.h>
#include <stdint.h>

#define NG 512            // graphs
#define NN 39             // nodes per graph
#define FIN0 39           // input features
#define HID 256
#define KNN 10
#define NROWS (NG * NN)   // 19968
#define BNEPS 1e-5f

typedef __hip_bfloat16 bf16;
typedef __attribute__((ext_vector_type(8))) short s16x8;
typedef __attribute__((ext_vector_type(4))) float f32x4;

__device__ __forceinline__ void gld_lds16(const void* g, void* l) {
  __builtin_amdgcn_global_load_lds(
      (const __attribute__((address_space(1))) void*)(uintptr_t)g,
      (__attribute__((address_space(3))) void*)(uintptr_t)l, 16, 0, 0);
}

__device__ __forceinline__ void split_bf16(float v, bf16& hi, bf16& lo) {
  hi = __float2bfloat16(v);
  lo = __float2bfloat16(v - __bfloat162float(hi));
}

// ---------------------------------------------------------------------------
// prep: A1 = split-bf16(x) zero-padded to K=64; W*T = folded+transposed
// split-bf16 weights. WT layout [512 outcols][K]: col<256 -> W_top - W_bot
// (u-half), col>=256 -> W_bot (v-half).
// ---------------------------------------------------------------------------
__global__ void k_prep(const float* __restrict__ x, const float* __restrict__ W1,
                       const float* __restrict__ W2, const float* __restrict__ W3,
                       bf16* __restrict__ A1h, bf16* __restrict__ A1l,
                       bf16* __restrict__ W1Th, bf16* __restrict__ W1Tl,
                       bf16* __restrict__ W2Th, bf16* __restrict__ W2Tl,
                       bf16* __restrict__ W3Th, bf16* __restrict__ W3Tl) {
  const int i = blockIdx.x * 256 + threadIdx.x;
  const int nA1 = NROWS * 64;
  if (i < nA1) {
    const int r = i >> 6, k = i & 63;
    const float v = (k < FIN0) ? x[r * FIN0 + k] : 0.f;
    split_bf16(v, A1h[i], A1l[i]);
    return;
  }
  int j = i - nA1;                       // W1T: [512][64]
  if (j < 512 * 64) {
    const int c = j >> 6, k = j & 63;
    float v = 0.f;
    if (k < FIN0)
      v = (c < HID) ? (W1[k * HID + c] - W1[(FIN0 + k) * HID + c])
                    : W1[(FIN0 + k) * HID + (c - HID)];
    split_bf16(v, W1Th[j], W1Tl[j]);
    return;
  }
  j -= 512 * 64;                         // W2T: [512][256]
  if (j < 512 * 256) {
    const int c = j >> 8, k = j & 255;
    const float v = (c < HID) ? (W2[k * HID + c] - W2[(HID + k) * HID + c])
                              : W2[(HID + k) * HID + (c - HID)];
    split_bf16(v, W2Th[j], W2Tl[j]);
    return;
  }
  j -= 512 * 256;                        // W3T: [512][256]
  if (j < 512 * 256) {
    const int c = j >> 8, k = j & 255;
    const float v = (c < HID) ? (W3[k * HID + c] - W3[(HID + k) * HID + c])
                              : W3[(HID + k) * HID + (c - HID)];
    split_bf16(v, W3Th[j], W3Tl[j]);
  }
}

// ---------------------------------------------------------------------------
// GEMM (split-bf16, near-f32): uv[M][512] = A[M][K] @ WT[512][K]^T (+bias on
// cols<256). acc += Ah*Bh + Ah*Bl + Al*Bh. 128x128 tile, BK=64, 4 waves,
// mfma 16x16x32 bf16. LDS granule-XOR swizzle; global source pre-swizzled so
// global_load_lds (linear dest) matches.
// ---------------------------------------------------------------------------
__global__ __launch_bounds__(256) void k_gemm(const bf16* __restrict__ Ah,
                                              const bf16* __restrict__ Al,
                                              const bf16* __restrict__ Bh,
                                              const bf16* __restrict__ Bl,
                                              const float* __restrict__ bias,
                                              float* __restrict__ uv, int K) {
  __shared__ bf16 As[2][128 * 64];
  __shared__ bf16 Bs[2][128 * 64];
  const int tid = threadIdx.x;
  const int wv = tid >> 6, ln = tid & 63;
  const int m0 = blockIdx.x * 128, c0 = blockIdx.y * 128;
  const int wm = wv >> 1, wn = wv & 1;
  const int fr = ln & 15, fq = ln >> 4;
  f32x4 acc[4][4];
#pragma unroll
  for (int m = 0; m < 4; m++)
#pragma unroll
    for (int n = 0; n < 4; n++) acc[m][n] = (f32x4){0.f, 0.f, 0.f, 0.f};

  for (int k0 = 0; k0 < K; k0 += 64) {
    __syncthreads();
#pragma unroll
    for (int p = 0; p < 4; p++) {
      const int r = p * 32 + wv * 8 + (ln >> 3);
      const int g = (((ln & 7) ^ (r & 7)) << 3);
      const int ldsoff = (p * 32 + wv * 8) * 64;
      gld_lds16(Ah + (size_t)(m0 + r) * K + k0 + g, &As[0][ldsoff]);
      gld_lds16(Al + (size_t)(m0 + r) * K + k0 + g, &As[1][ldsoff]);
      gld_lds16(Bh + (size_t)(c0 + r) * K + k0 + g, &Bs[0][ldsoff]);
      gld_lds16(Bl + (size_t)(c0 + r) * K + k0 + g, &Bs[1][ldsoff]);
    }
    __syncthreads();
#pragma unroll
    for (int kk = 0; kk < 2; kk++) {
      s16x8 av[2][4], bv[2][4];
#pragma unroll
      for (int m = 0; m < 4; m++) {
        const int row = wm * 64 + m * 16 + fr;
        const int co = row * 64 + (((kk * 4 + fq) ^ (row & 7)) << 3);
        av[0][m] = *(const s16x8*)&As[0][co];
        av[1][m] = *(const s16x8*)&As[1][co];
      }
#pragma unroll
      for (int n = 0; n < 4; n++) {
        const int row = wn * 64 + n * 16 + fr;
        const int co = row * 64 + (((kk * 4 + fq) ^ (row & 7)) << 3);
        bv[0][n] = *(const s16x8*)&Bs[0][co];
        bv[1][n] = *(const s16x8*)&Bs[1][co];
      }
#pragma unroll
      for (int m = 0; m < 4; m++)
#pragma unroll
        for (int n = 0; n < 4; n++) {
          acc[m][n] = __builtin_amdgcn_mfma_f32_16x16x32_bf16(av[0][m], bv[0][n], acc[m][n], 0, 0, 0);
          acc[m][n] = __builtin_amdgcn_mfma_f32_16x16x32_bf16(av[0][m], bv[1][n], acc[m][n], 0, 0, 0);
          acc[m][n] = __builtin_amdgcn_mfma_f32_16x16x32_bf16(av[1][m], bv[0][n], acc[m][n], 0, 0, 0);
        }
    }
  }
#pragma unroll
  for (int n = 0; n < 4; n++) {
    const int col = c0 + wn * 64 + n * 16 + fr;
    const float bb = (col < HID) ? bias[col] : 0.f;
#pragma unroll
    for (int m = 0; m < 4; m++) {
      const int row = m0 + wm * 64 + m * 16 + fq * 4;
#pragma unroll
      for (int r = 0; r < 4; r++)
        uv[(size_t)(row + r) * 512 + col] = acc[m][n][r] + bb;
    }
  }
}

// ---------------------------------------------------------------------------
// Edge kernel: one block per graph. Loads features (BN+relu on the fly for
// layers 2/3), builds f32 kNN (Gram -> d_ij = G_ii+G_jj-2G_ij, top-10 with
// stable tie-break), then h[n][c] = relu(u[n][c] + max_k v[idx][c]).
// Writes h_pre and per-graph channel sum/sumsq partials.
// ---------------------------------------------------------------------------
template <int FIN>
__global__ __launch_bounds__(256) void k_edge(const float* __restrict__ fin,
                                              const float* __restrict__ stats,
                                              const float* __restrict__ uv,
                                              float* __restrict__ h_out,
                                              float* __restrict__ part) {
  constexpr int CHW = (FIN == 39) ? 64 : 256;  // physical floats per hn row
  constexpr int NCH = (FIN == 39) ? 10 : 64;   // logical 16B chunks in dot
  __shared__ __align__(16) float hn[NN * CHW];
  __shared__ __align__(16) float vsh[NN][HID];
  __shared__ float dmat[NN][NN + 1];
  __shared__ float sqv[NN];
  __shared__ int idxs[NN][KNN];
  __shared__ float red[8][HID];
  const int b = blockIdx.x, tid = threadIdx.x;
  const int wv = tid >> 6, ln = tid & 63;
  const size_t base = (size_t)b * NN;

  if (FIN == 39) {
    for (int t = tid; t < NN * CHW; t += 256) hn[t] = 0.f;
    __syncthreads();
  }
  // features -> swizzled LDS (chunk ^= n&15 to kill row-stride bank conflicts)
  for (int t = tid; t < NN * FIN; t += 256) {
    const int n = t / FIN, f = t - n * FIN;
    float v = fin[base * FIN + t];
    if (FIN != 39) v = fmaxf(v * stats[f] + stats[HID + f], 0.f);
    hn[n * CHW + (((f >> 2) ^ (n & 15)) << 2) + (f & 3)] = v;
  }
  // v-half of uv -> LDS
  for (int t = tid; t < NN * HID; t += 256) {
    const int n = t >> 8, c = t & 255;
    vsh[n][c] = uv[(base + n) * 512 + HID + c];
  }
  __syncthreads();

  // Gram: wave per row i, lane per col j
  for (int i = wv; i < NN; i += 4) {
    if (ln < NN) {
      const int j = ln;
      float dot = 0.f;
#pragma unroll 4
      for (int cc = 0; cc < NCH; cc++) {
        const f32x4 xi = *(const f32x4*)&hn[i * CHW + ((cc ^ (i & 15)) << 2)];
        const f32x4 xj = *(const f32x4*)&hn[j * CHW + ((cc ^ (j & 15)) << 2)];
        dot += xi[0] * xj[0] + xi[1] * xj[1] + xi[2] * xj[2] + xi[3] * xj[3];
      }
      dmat[i][j] = dot;
    }
  }
  __syncthreads();
  if (tid < NN) sqv[tid] = dmat[tid][tid];
  __syncthreads();
  for (int p = tid; p < NN * NN; p += 256) {
    const int i = p / NN, j = p - i * NN;
    dmat[i][j] = sqv[i] + sqv[j] - 2.f * dmat[i][j];   // d_ii == 0 exactly
  }
  __syncthreads();
  // top-KNN smallest per row; strict < picks lowest index on ties (= lax.top_k)
  if (tid < NN) {
    unsigned long long taken = 0ull;
    for (int k = 0; k < KNN; k++) {
      float best = 3.4e38f;
      int bj = 0;
      for (int j = 0; j < NN; j++) {
        const float dv = dmat[tid][j];
        if (!((taken >> j) & 1ull) && dv < best) { best = dv; bj = j; }
      }
      taken |= 1ull << bj;
      idxs[tid][k] = bj;
    }
  }
  __syncthreads();

  // h[n][c] = relu(u + max_k v); float4 per lane over channels
  const int cl = ln * 4;
  f32x4 s1 = {0.f, 0.f, 0.f, 0.f}, s2 = {0.f, 0.f, 0.f, 0.f};
  for (int n0 = 0; n0 < NN; n0 += 4) {
    const int n = n0 + wv;
    if (n < NN) {
      const f32x4 u = *(const f32x4*)&uv[(base + n) * 512 + cl];
      f32x4 vm = {-3.4e38f, -3.4e38f, -3.4e38f, -3.4e38f};
#pragma unroll
      for (int k = 0; k < KNN; k++) {
        const f32x4 vvv = *(const f32x4*)&vsh[idxs[n][k]][cl];
        vm[0] = fmaxf(vm[0], vvv[0]); vm[1] = fmaxf(vm[1], vvv[1]);
        vm[2] = fmaxf(vm[2], vvv[2]); vm[3] = fmaxf(vm[3], vvv[3]);
      }
      f32x4 h;
#pragma unroll
      for (int t2 = 0; t2 < 4; t2++) h[t2] = fmaxf(u[t2] + vm[t2], 0.f);
      *(f32x4*)&h_out[(base + n) * HID + cl] = h;
#pragma unroll
      for (int t2 = 0; t2 < 4; t2++) { s1[t2] += h[t2]; s2[t2] += h[t2] * h[t2]; }
    }
  }
#pragma unroll
  for (int t2 = 0; t2 < 4; t2++) { red[wv][cl + t2] = s1[t2]; red[4 + wv][cl + t2] = s2[t2]; }
  __syncthreads();
  if (tid < HID) {
    part[(size_t)b * 512 + tid] = red[0][tid] + red[1][tid] + red[2][tid] + red[3][tid];
    part[(size_t)b * 512 + HID + tid] = red[4][tid] + red[5][tid] + red[6][tid] + red[7][tid];
  }
}

// fixed-order stats reduce -> scale/shift (fold gamma/beta): BN(x)=x*sc+sh
__global__ void k_stats(const float* __restrict__ part, const float* __restrict__ gam,
                        const float* __restrict__ bet, float* __restrict__ st) {
  const int c = threadIdx.x;
  float s = 0.f, s2 = 0.f;
  for (int g = 0; g < NG; g++) { s += part[g * 512 + c]; s2 += part[g * 512 + HID + c]; }
  const float mean = s * (1.f / NROWS);
  const float var = s2 * (1.f / NROWS) - mean * mean;
  const float sc = gam[c] * rsqrtf(var + BNEPS);
  st[c] = sc;
  st[HID + c] = bet[c] - mean * sc;
}

// A = split-bf16(relu(h*sc+sh))  (next layer's GEMM input)
__global__ void k_bnrelu(const float* __restrict__ h, const float* __restrict__ st,
                         bf16* __restrict__ Ah, bf16* __restrict__ Al) {
  const size_t e = ((size_t)blockIdx.x * 256 + threadIdx.x) * 4;
  const int c = (int)(e & 255);
  const f32x4 v = *(const f32x4*)(h + e);
  union { bf16 b[4]; uint64_t u; } ph, pl;
#pragma unroll
  for (int t = 0; t < 4; t++) {
    const float r = fmaxf(v[t] * st[c + t] + st[HID + c + t], 0.f);
    split_bf16(r, ph.b[t], pl.b[t]);
  }
  *(uint64_t*)(Ah + e) = ph.u;
  *(uint64_t*)(Al + e) = pl.u;
}

// pooled = BN(mean_n h3) (affine commutes with mean; no relu); logits; softmax
__global__ __launch_bounds__(256) void k_final(const float* __restrict__ h3,
                                               const float* __restrict__ st,
                                               const float* __restrict__ Wl,
                                               const float* __restrict__ bl,
                                               float* __restrict__ out) {
  __shared__ float r0[HID], r1[HID];
  const int b = blockIdx.x, c = threadIdx.x;
  float s = 0.f;
  for (int n = 0; n < NN; n++) s += h3[((size_t)b * NN + n) * HID + c];
  const float pooled = (s * (1.f / NN)) * st[c] + st[HID + c];
  r0[c] = pooled * Wl[c * 2 + 0];
  r1[c] = pooled * Wl[c * 2 + 1];
  __syncthreads();
  for (int stp = 128; stp > 0; stp >>= 1) {
    if (c < stp) { r0[c] += r0[c + stp]; r1[c] += r1[c + stp]; }
    __syncthreads();
  }
  if (c == 0) {
    const float l0 = r0[0] + bl[0], l1 = r1[0] + bl[1];
    const float mx = fmaxf(l0, l1);
    const float e0 = expf(l0 - mx), e1 = expf(l1 - mx);
    const float inv = 1.f / (e0 + e1);
    out[b * 2 + 0] = e0 * inv;
    out[b * 2 + 1] = e1 * inv;
  }
}

extern "C" void kernel_launch(void* const* d_in, const int* in_sizes, int n_in,
                              void* d_out, int out_size, void* d_ws, size_t ws_size,
                              hipStream_t stream) {
  const float* x   = (const float*)d_in[0];
  // d_in[1] = batch (structure is fixed: repeat(arange(512), 39)) -- unused
  const float* W1  = (const float*)d_in[2];
  const float* b1  = (const float*)d_in[3];
  const float* W2  = (const float*)d_in[4];
  const float* b2  = (const float*)d_in[5];
  const float* W3  = (const float*)d_in[6];
  const float* b3  = (const float*)d_in[7];
  const float* g1  = (const float*)d_in[8];
  const float* be1 = (const float*)d_in[9];
  const float* g2  = (const float*)d_in[10];
  const float* be2 = (const float*)d_in[11];
  const float* g3  = (const float*)d_in[12];
  const float* be3 = (const float*)d_in[13];
  const float* Wl  = (const float*)d_in[14];
  const float* bl  = (const float*)d_in[15];

  char* ws = (char*)d_ws;
  size_t off = 0;
  auto alloc = [&](size_t bytes) {
    size_t o = off;
    off += (bytes + 255) & ~(size_t)255;
    return o;
  };
  bf16* Ah   = (bf16*)(ws + alloc((size_t)NROWS * HID * 2));   // GEMM input hi (A1 uses [.][64] prefix)
  bf16* Al   = (bf16*)(ws + alloc((size_t)NROWS * HID * 2));   // GEMM input lo
  bf16* W1Th = (bf16*)(ws + alloc(512 * 64 * 2));
  bf16* W1Tl = (bf16*)(ws + alloc(512 * 64 * 2));
  bf16* W2Th = (bf16*)(ws + alloc(512 * 256 * 2));
  bf16* W2Tl = (bf16*)(ws + alloc(512 * 256 * 2));
  bf16* W3Th = (bf16*)(ws + alloc(512 * 256 * 2));
  bf16* W3Tl = (bf16*)(ws + alloc(512 * 256 * 2));
  float* uv  = (float*)(ws + alloc((size_t)NROWS * 512 * 4));
  float* hA  = (float*)(ws + alloc((size_t)NROWS * HID * 4));
  float* hB  = (float*)(ws + alloc((size_t)NROWS * HID * 4));
  float* part = (float*)(ws + alloc((size_t)NG * 512 * 4));
  float* st1 = (float*)(ws + alloc(512 * 4));
  float* st2 = (float*)(ws + alloc(512 * 4));
  float* st3 = (float*)(ws + alloc(512 * 4));
  if (off > ws_size) return;  // workspace too small -> visible failure

  const dim3 gemm_grid(NROWS / 128, 4);

  k_prep<<<6144, 256, 0, stream>>>(x, W1, W2, W3, Ah, Al, W1Th, W1Tl, W2Th, W2Tl, W3Th, W3Tl);

  // layer 1
  k_gemm<<<gemm_grid, 256, 0, stream>>>(Ah, Al, W1Th, W1Tl, b1, uv, 64);
  k_edge<39><<<NG, 256, 0, stream>>>(x, nullptr, uv, hA, part);
  k_stats<<<1, 256, 0, stream>>>(part, g1, be1, st1);

  // layer 2
  k_bnrelu<<<NROWS * HID / 1024, 256, 0, stream>>>(hA, st1, Ah, Al);
  k_gemm<<<gemm_grid, 256, 0, stream>>>(Ah, Al, W2Th, W2Tl, b2, uv, 256);
  k_edge<256><<<NG, 256, 0, stream>>>(hA, st1, uv, hB, part);
  k_stats<<<1, 256, 0, stream>>>(part, g2, be2, st2);

  // layer 3
  k_bnrelu<<<NROWS * HID / 1024, 256, 0, stream>>>(hB, st2, Ah, Al);
  k_gemm<<<gemm_grid, 256, 0, stream>>>(Ah, Al, W3Th, W3Tl, b3, uv, 256);
  k_edge<256><<<NG, 256, 0, stream>>>(hB, st2, uv, hA, part);
  k_stats<<<1, 256, 0, stream>>>(part, g3, be3, st3);

  // pool + linear + softmax
  k_final<<<NG, 256, 0, stream>>>(hA, st3, Wl, bl, (float*)d_out);
}

// Round 3
// 170.484 us; speedup vs baseline: 2.0848x; 2.0848x over previous
//
#include <hip/hip_runtime.h>
#include <hip/hip_bf16.h>
#include <stdint.h>

#define NG 512            // graphs
#define NN 39             // nodes per graph
#define FIN0 39           // input features
#define HID 256
#define KNN 10
#define NROWS (NG * NN)   // 19968
#define BNEPS 1e-5f

typedef __hip_bfloat16 bf16;
typedef __attribute__((ext_vector_type(8))) short s16x8;
typedef __attribute__((ext_vector_type(4))) float f32x4;

__device__ __forceinline__ void gld_lds16(const void* g, void* l) {
  __builtin_amdgcn_global_load_lds(
      (const __attribute__((address_space(1))) void*)(uintptr_t)g,
      (__attribute__((address_space(3))) void*)(uintptr_t)l, 16, 0, 0);
}

__device__ __forceinline__ void split_bf16(float v, bf16& hi, bf16& lo) {
  hi = __float2bfloat16(v);
  lo = __float2bfloat16(v - __bfloat162float(hi));
}

// ---------------------------------------------------------------------------
// prep: A1 = split-bf16(x) zero-padded to K=64; W*T = folded+transposed
// split-bf16 weights. WT layout [512 outcols][K]: col<256 -> W_top - W_bot
// (u-half), col>=256 -> W_bot (v-half). 4 elems/thread, packed u64 stores.
// ---------------------------------------------------------------------------
__global__ void k_prep(const float* __restrict__ x, const float* __restrict__ W1,
                       const float* __restrict__ W2, const float* __restrict__ W3,
                       bf16* __restrict__ A1h, bf16* __restrict__ A1l,
                       bf16* __restrict__ W1Th, bf16* __restrict__ W1Tl,
                       bf16* __restrict__ W2Th, bf16* __restrict__ W2Tl,
                       bf16* __restrict__ W3Th, bf16* __restrict__ W3Tl) {
  const int i = (blockIdx.x * 256 + threadIdx.x) * 4;
  const int nA1 = NROWS * 64;
  union U { bf16 b[4]; uint64_t u; };
  U h, l;
  if (i < nA1) {
    const int r = i >> 6, k = i & 63;
#pragma unroll
    for (int t = 0; t < 4; t++) {
      const float v = (k + t < FIN0) ? x[r * FIN0 + k + t] : 0.f;
      split_bf16(v, h.b[t], l.b[t]);
    }
    *(uint64_t*)(A1h + i) = h.u; *(uint64_t*)(A1l + i) = l.u;
    return;
  }
  int j = i - nA1;                       // W1T: [512][64]
  if (j < 512 * 64) {
    const int c = j >> 6, k = j & 63;
#pragma unroll
    for (int t = 0; t < 4; t++) {
      float v = 0.f;
      if (k + t < FIN0)
        v = (c < HID) ? (W1[(k + t) * HID + c] - W1[(FIN0 + k + t) * HID + c])
                      : W1[(FIN0 + k + t) * HID + (c - HID)];
      split_bf16(v, h.b[t], l.b[t]);
    }
    *(uint64_t*)(W1Th + j) = h.u; *(uint64_t*)(W1Tl + j) = l.u;
    return;
  }
  j -= 512 * 64;                         // W2T: [512][256]
  if (j < 512 * 256) {
    const int c = j >> 8, k = j & 255;
#pragma unroll
    for (int t = 0; t < 4; t++) {
      const float v = (c < HID) ? (W2[(k + t) * HID + c] - W2[(HID + k + t) * HID + c])
                                : (W2[(HID + k + t) * HID + (c - HID)]);
      split_bf16(v, h.b[t], l.b[t]);
    }
    *(uint64_t*)(W2Th + j) = h.u; *(uint64_t*)(W2Tl + j) = l.u;
    return;
  }
  j -= 512 * 256;                        // W3T: [512][256]
  if (j < 512 * 256) {
    const int c = j >> 8, k = j & 255;
#pragma unroll
    for (int t = 0; t < 4; t++) {
      const float v = (c < HID) ? (W3[(k + t) * HID + c] - W3[(HID + k + t) * HID + c])
                                : (W3[(HID + k + t) * HID + (c - HID)]);
      split_bf16(v, h.b[t], l.b[t]);
    }
    *(uint64_t*)(W3Th + j) = h.u; *(uint64_t*)(W3Tl + j) = l.u;
  }
}

// ---------------------------------------------------------------------------
// GEMM (split-bf16, near-f32): uv[M][512] = A[M][K] @ WT[512][K]^T (+bias on
// cols<256). acc += Ah*Bh + Ah*Bl + Al*Bh. 128x128 tile, BK=64, 4 waves,
// mfma 16x16x32 bf16. LDS granule-XOR swizzle; global source pre-swizzled so
// global_load_lds (linear dest) matches.  (unchanged from R2 — verified)
// ---------------------------------------------------------------------------
__global__ __launch_bounds__(256) void k_gemm(const bf16* __restrict__ Ah,
                                              const bf16* __restrict__ Al,
                                              const bf16* __restrict__ Bh,
                                              const bf16* __restrict__ Bl,
                                              const float* __restrict__ bias,
                                              float* __restrict__ uv, int K) {
  __shared__ bf16 As[2][128 * 64];
  __shared__ bf16 Bs[2][128 * 64];
  const int tid = threadIdx.x;
  const int wv = tid >> 6, ln = tid & 63;
  const int m0 = blockIdx.x * 128, c0 = blockIdx.y * 128;
  const int wm = wv >> 1, wn = wv & 1;
  const int fr = ln & 15, fq = ln >> 4;
  f32x4 acc[4][4];
#pragma unroll
  for (int m = 0; m < 4; m++)
#pragma unroll
    for (int n = 0; n < 4; n++) acc[m][n] = (f32x4){0.f, 0.f, 0.f, 0.f};

  for (int k0 = 0; k0 < K; k0 += 64) {
    __syncthreads();
#pragma unroll
    for (int p = 0; p < 4; p++) {
      const int r = p * 32 + wv * 8 + (ln >> 3);
      const int g = (((ln & 7) ^ (r & 7)) << 3);
      const int ldsoff = (p * 32 + wv * 8) * 64;
      gld_lds16(Ah + (size_t)(m0 + r) * K + k0 + g, &As[0][ldsoff]);
      gld_lds16(Al + (size_t)(m0 + r) * K + k0 + g, &As[1][ldsoff]);
      gld_lds16(Bh + (size_t)(c0 + r) * K + k0 + g, &Bs[0][ldsoff]);
      gld_lds16(Bl + (size_t)(c0 + r) * K + k0 + g, &Bs[1][ldsoff]);
    }
    __syncthreads();
#pragma unroll
    for (int kk = 0; kk < 2; kk++) {
      s16x8 av[2][4], bv[2][4];
#pragma unroll
      for (int m = 0; m < 4; m++) {
        const int row = wm * 64 + m * 16 + fr;
        const int co = row * 64 + (((kk * 4 + fq) ^ (row & 7)) << 3);
        av[0][m] = *(const s16x8*)&As[0][co];
        av[1][m] = *(const s16x8*)&As[1][co];
      }
#pragma unroll
      for (int n = 0; n < 4; n++) {
        const int row = wn * 64 + n * 16 + fr;
        const int co = row * 64 + (((kk * 4 + fq) ^ (row & 7)) << 3);
        bv[0][n] = *(const s16x8*)&Bs[0][co];
        bv[1][n] = *(const s16x8*)&Bs[1][co];
      }
#pragma unroll
      for (int m = 0; m < 4; m++)
#pragma unroll
        for (int n = 0; n < 4; n++) {
          acc[m][n] = __builtin_amdgcn_mfma_f32_16x16x32_bf16(av[0][m], bv[0][n], acc[m][n], 0, 0, 0);
          acc[m][n] = __builtin_amdgcn_mfma_f32_16x16x32_bf16(av[0][m], bv[1][n], acc[m][n], 0, 0, 0);
          acc[m][n] = __builtin_amdgcn_mfma_f32_16x16x32_bf16(av[1][m], bv[0][n], acc[m][n], 0, 0, 0);
        }
    }
  }
#pragma unroll
  for (int n = 0; n < 4; n++) {
    const int col = c0 + wn * 64 + n * 16 + fr;
    const float bb = (col < HID) ? bias[col] : 0.f;
#pragma unroll
    for (int m = 0; m < 4; m++) {
      const int row = m0 + wm * 64 + m * 16 + fq * 4;
#pragma unroll
      for (int r = 0; r < 4; r++)
        uv[(size_t)(row + r) * 512 + col] = acc[m][n][r] + bb;
    }
  }
}

// ---------------------------------------------------------------------------
// Edge kernel v2: one block (256 thr) per graph.
//  phase0: stage split-bf16 features (Ah/Al rows of this graph) -> LDS via
//          global_load_lds, rows 39..47 zeroed.
//  phase1: Gram via MFMA (3-product split) using k_gemm's verified fragment
//          pattern. d_ii == 0 exactly.
//  phase2: distances in-place; phase3: async v-stage + 4-lane-group top-10;
//  phase4: h = relu(u + max_k v) + per-graph BN partials.
// LDS ~56KB -> 2 blocks/CU.
// ---------------------------------------------------------------------------
template <int K>   // 64 (layer1) or 256 (layers 2/3)
__global__ __launch_bounds__(256) void k_edge(const bf16* __restrict__ Ah,
                                              const bf16* __restrict__ Al,
                                              const float* __restrict__ uv,
                                              float* __restrict__ h_out,
                                              float* __restrict__ part) {
  constexpr int GPR = K / 8;                       // 16B granules per row
  constexpr int XREG = (K == 256) ? 49152 : 48128; // bytes: X-tiles / {vsh,red}
  __shared__ __align__(16) char smem[XREG + 6240 + 160 + 1568];
  bf16* Xh = (bf16*)smem;                 // [48][K]
  bf16* Xl = Xh + 48 * K;                 // [48][K]
  float* vsh = (float*)smem;              // [39][256] (aliases X, phase>=3)
  float* red = (float*)(smem + 39936);    // [8][256]  (aliases X, phase>=4)
  float* dmat = (float*)(smem + XREG);    // [39][40]
  float* sqv  = (float*)(smem + XREG + 6240);      // [39]
  int*   idxs = (int*)(smem + XREG + 6240 + 160);  // [39][10]

  const int b = blockIdx.x, tid = threadIdx.x;
  const int wv = tid >> 6, ln = tid & 63;
  const int fr = ln & 15, fq = ln >> 4;
  const size_t base = (size_t)b * NN;

  // ---- phase 0: stage X (pre-swizzled source, linear LDS dest) ----
  for (int t0 = 0; t0 < 48 * GPR; t0 += 256) {
    const int t = t0 + tid;
    if (t < 48 * GPR) {
      const int row = t / GPR, g = t % GPR;
      bf16* dh = Xh + (size_t)(t0 + wv * 64) * 8;   // wave-uniform base
      bf16* dl = Xl + (size_t)(t0 + wv * 64) * 8;
      if (row < NN) {
        const size_t src = (size_t)(base + row) * K + ((g ^ (row & 7)) << 3);
        gld_lds16(Ah + src, dh);
        gld_lds16(Al + src, dl);
      } else {
        *(f32x4*)(Xh + (size_t)t * 8) = (f32x4){0.f, 0.f, 0.f, 0.f};
        *(f32x4*)(Xl + (size_t)t * 8) = (f32x4){0.f, 0.f, 0.f, 0.f};
      }
    }
  }
  __syncthreads();

  // ---- phase 1: Gram via MFMA (pairs of 16x16 tiles) ----
  for (int p = wv; p < 9; p += 4) {
    const int mi = p / 3, ni = p % 3;
    f32x4 acc = (f32x4){0.f, 0.f, 0.f, 0.f};
    const int ar = mi * 16 + fr, br = ni * 16 + fr;
#pragma unroll
    for (int ks = 0; ks < K / 32; ks++) {
      const int ga = ((ks * 4 + fq) ^ (ar & 7)) << 3;
      const int gb = ((ks * 4 + fq) ^ (br & 7)) << 3;
      const s16x8 avh = *(const s16x8*)&Xh[ar * K + ga];
      const s16x8 avl = *(const s16x8*)&Xl[ar * K + ga];
      const s16x8 bvh = *(const s16x8*)&Xh[br * K + gb];
      const s16x8 bvl = *(const s16x8*)&Xl[br * K + gb];
      acc = __builtin_amdgcn_mfma_f32_16x16x32_bf16(avh, bvh, acc, 0, 0, 0);
      acc = __builtin_amdgcn_mfma_f32_16x16x32_bf16(avh, bvl, acc, 0, 0, 0);
      acc = __builtin_amdgcn_mfma_f32_16x16x32_bf16(avl, bvh, acc, 0, 0, 0);
    }
    const int oc = ni * 16 + fr;           // C layout: col=lane&15
    if (oc < NN) {
#pragma unroll
      for (int r = 0; r < 4; r++) {        // row=(lane>>4)*4+reg
        const int orow = mi * 16 + fq * 4 + r;
        if (orow < NN) dmat[orow * 40 + oc] = acc[r];
      }
    }
  }
  __syncthreads();

  // ---- phase 2: distances in place ----
  if (tid < NN) sqv[tid] = dmat[tid * 40 + tid];
  __syncthreads();
  for (int t = tid; t < NN * NN; t += 256) {
    const int i = t / NN, j = t - i * NN;
    dmat[i * 40 + j] = sqv[i] + sqv[j] - 2.f * dmat[i * 40 + j];
  }
  __syncthreads();

  // ---- phase 3a: async-stage v-half of uv into vsh (X is dead) ----
  for (int t0 = 0; t0 < NN * 64; t0 += 256) {
    const int t = t0 + tid;
    if (t < NN * 64) {
      const int n = t >> 6, cc = t & 63;
      float* dst = vsh + (size_t)(t0 + wv * 64) * 4;  // wave-uniform base
      gld_lds16(uv + (size_t)(base + n) * 512 + HID + cc * 4, dst);
    }
  }

  // ---- phase 3b: top-10 per row, 4-lane groups (overlaps with 3a loads) ----
  const int grp = tid >> 2, l4 = tid & 3;
  if (grp < NN) {
    float dv[10];
#pragma unroll
    for (int s = 0; s < 10; s++) {
      const int j = l4 + s * 4;
      dv[s] = (j < NN) ? dmat[grp * 40 + j] : 3.4e38f;
    }
    unsigned taken = 0;
    for (int k = 0; k < KNN; k++) {
      float bv = 3.4e38f;
      int bi = 1 << 30;
#pragma unroll
      for (int s = 0; s < 10; s++) {
        const float v = ((taken >> s) & 1u) ? 3.4e38f : dv[s];
        const int j = l4 + s * 4;
        if (v < bv || (v == bv && j < bi)) { bv = v; bi = j; }
      }
#pragma unroll
      for (int m = 1; m < 4; m <<= 1) {
        const float ov = __shfl_xor(bv, m, 64);
        const int oi = __shfl_xor(bi, m, 64);
        if (ov < bv || (ov == bv && oi < bi)) { bv = ov; bi = oi; }
      }
      if ((bi & 3) == l4) taken |= 1u << (bi >> 2);
      if (l4 == 0) idxs[grp * 10 + k] = bi;
    }
  }
  __syncthreads();   // idxs ready + vsh loads drained

  // ---- phase 4: h[n][c] = relu(u + max_k v); BN partials ----
  const int cl = ln * 4;
  f32x4 s1 = (f32x4){0.f, 0.f, 0.f, 0.f}, s2 = (f32x4){0.f, 0.f, 0.f, 0.f};
  for (int n0 = 0; n0 < NN; n0 += 4) {
    const int n = n0 + wv;
    if (n < NN) {
      const f32x4 u = *(const f32x4*)&uv[(size_t)(base + n) * 512 + cl];
      f32x4 vm = (f32x4){-3.4e38f, -3.4e38f, -3.4e38f, -3.4e38f};
#pragma unroll
      for (int k = 0; k < KNN; k++) {
        const f32x4 vvv = *(const f32x4*)&vsh[idxs[n * 10 + k] * HID + cl];
        vm[0] = fmaxf(vm[0], vvv[0]); vm[1] = fmaxf(vm[1], vvv[1]);
        vm[2] = fmaxf(vm[2], vvv[2]); vm[3] = fmaxf(vm[3], vvv[3]);
      }
      f32x4 h;
#pragma unroll
      for (int t2 = 0; t2 < 4; t2++) h[t2] = fmaxf(u[t2] + vm[t2], 0.f);
      *(f32x4*)&h_out[(size_t)(base + n) * HID + cl] = h;
#pragma unroll
      for (int t2 = 0; t2 < 4; t2++) { s1[t2] += h[t2]; s2[t2] += h[t2] * h[t2]; }
    }
  }
#pragma unroll
  for (int t2 = 0; t2 < 4; t2++) { red[wv * HID + cl + t2] = s1[t2]; red[(4 + wv) * HID + cl + t2] = s2[t2]; }
  __syncthreads();
  if (tid < HID) {
    part[(size_t)b * 512 + tid] =
        red[0 * HID + tid] + red[1 * HID + tid] + red[2 * HID + tid] + red[3 * HID + tid];
    part[(size_t)b * 512 + HID + tid] =
        red[4 * HID + tid] + red[5 * HID + tid] + red[6 * HID + tid] + red[7 * HID + tid];
  }
}

// stats reduce: one block per channel; deterministic tree order.
__global__ __launch_bounds__(256) void k_stats(const float* __restrict__ part,
                                               const float* __restrict__ gam,
                                               const float* __restrict__ bet,
                                               float* __restrict__ st) {
  __shared__ float rs[4], rq[4];
  const int c = blockIdx.x, tid = threadIdx.x;
  float s = part[(size_t)tid * 512 + c] + part[(size_t)(tid + 256) * 512 + c];
  float q = part[(size_t)tid * 512 + HID + c] + part[(size_t)(tid + 256) * 512 + HID + c];
#pragma unroll
  for (int m = 32; m >= 1; m >>= 1) { s += __shfl_down(s, m, 64); q += __shfl_down(q, m, 64); }
  if ((tid & 63) == 0) { rs[tid >> 6] = s; rq[tid >> 6] = q; }
  __syncthreads();
  if (tid == 0) {
    s = rs[0] + rs[1] + rs[2] + rs[3];
    q = rq[0] + rq[1] + rq[2] + rq[3];
    const float mean = s * (1.f / NROWS);
    const float var = q * (1.f / NROWS) - mean * mean;
    const float sc = gam[c] * rsqrtf(var + BNEPS);
    st[c] = sc;
    st[HID + c] = bet[c] - mean * sc;
  }
}

// A = split-bf16(relu(h*sc+sh))  (next layer's GEMM + kNN input)
__global__ void k_bnrelu(const float* __restrict__ h, const float* __restrict__ st,
                         bf16* __restrict__ Ah, bf16* __restrict__ Al) {
  const size_t e = ((size_t)blockIdx.x * 256 + threadIdx.x) * 4;
  const int c = (int)(e & 255);
  const f32x4 v = *(const f32x4*)(h + e);
  union { bf16 b[4]; uint64_t u; } ph, pl;
#pragma unroll
  for (int t = 0; t < 4; t++) {
    const float r = fmaxf(v[t] * st[c + t] + st[HID + c + t], 0.f);
    split_bf16(r, ph.b[t], pl.b[t]);
  }
  *(uint64_t*)(Ah + e) = ph.u;
  *(uint64_t*)(Al + e) = pl.u;
}

// pooled = BN(mean_n h3) (affine commutes with mean; no relu); logits; softmax
__global__ __launch_bounds__(256) void k_final(const float* __restrict__ h3,
                                               const float* __restrict__ st,
                                               const float* __restrict__ Wl,
                                               const float* __restrict__ bl,
                                               float* __restrict__ out) {
  __shared__ float r0[HID], r1[HID];
  const int b = blockIdx.x, c = threadIdx.x;
  float s = 0.f;
  for (int n = 0; n < NN; n++) s += h3[((size_t)b * NN + n) * HID + c];
  const float pooled = (s * (1.f / NN)) * st[c] + st[HID + c];
  r0[c] = pooled * Wl[c * 2 + 0];
  r1[c] = pooled * Wl[c * 2 + 1];
  __syncthreads();
  for (int stp = 128; stp > 0; stp >>= 1) {
    if (c < stp) { r0[c] += r0[c + stp]; r1[c] += r1[c + stp]; }
    __syncthreads();
  }
  if (c == 0) {
    const float l0 = r0[0] + bl[0], l1 = r1[0] + bl[1];
    const float mx = fmaxf(l0, l1);
    const float e0 = expf(l0 - mx), e1 = expf(l1 - mx);
    const float inv = 1.f / (e0 + e1);
    out[b * 2 + 0] = e0 * inv;
    out[b * 2 + 1] = e1 * inv;
  }
}

extern "C" void kernel_launch(void* const* d_in, const int* in_sizes, int n_in,
                              void* d_out, int out_size, void* d_ws, size_t ws_size,
                              hipStream_t stream) {
  const float* x   = (const float*)d_in[0];
  // d_in[1] = batch (structure fixed: repeat(arange(512), 39)) -- unused
  const float* W1  = (const float*)d_in[2];
  const float* b1  = (const float*)d_in[3];
  const float* W2  = (const float*)d_in[4];
  const float* b2  = (const float*)d_in[5];
  const float* W3  = (const float*)d_in[6];
  const float* b3  = (const float*)d_in[7];
  const float* g1  = (const float*)d_in[8];
  const float* be1 = (const float*)d_in[9];
  const float* g2  = (const float*)d_in[10];
  const float* be2 = (const float*)d_in[11];
  const float* g3  = (const float*)d_in[12];
  const float* be3 = (const float*)d_in[13];
  const float* Wl  = (const float*)d_in[14];
  const float* bl  = (const float*)d_in[15];

  char* ws = (char*)d_ws;
  size_t off = 0;
  auto alloc = [&](size_t bytes) {
    size_t o = off;
    off += (bytes + 255) & ~(size_t)255;
    return o;
  };
  bf16* Ah   = (bf16*)(ws + alloc((size_t)NROWS * HID * 2));   // split features hi (layer1: [.][64] prefix)
  bf16* Al   = (bf16*)(ws + alloc((size_t)NROWS * HID * 2));   // split features lo
  bf16* W1Th = (bf16*)(ws + alloc(512 * 64 * 2));
  bf16* W1Tl = (bf16*)(ws + alloc(512 * 64 * 2));
  bf16* W2Th = (bf16*)(ws + alloc(512 * 256 * 2));
  bf16* W2Tl = (bf16*)(ws + alloc(512 * 256 * 2));
  bf16* W3Th = (bf16*)(ws + alloc(512 * 256 * 2));
  bf16* W3Tl = (bf16*)(ws + alloc(512 * 256 * 2));
  float* uv  = (float*)(ws + alloc((size_t)NROWS * 512 * 4));
  float* hA  = (float*)(ws + alloc((size_t)NROWS * HID * 4));
  float* hB  = (float*)(ws + alloc((size_t)NROWS * HID * 4));
  float* part = (float*)(ws + alloc((size_t)NG * 512 * 4));
  float* st1 = (float*)(ws + alloc(512 * 4));
  float* st2 = (float*)(ws + alloc(512 * 4));
  float* st3 = (float*)(ws + alloc(512 * 4));
  if (off > ws_size) return;  // workspace too small -> visible failure

  const dim3 gemm_grid(NROWS / 128, 4);

  k_prep<<<1536, 256, 0, stream>>>(x, W1, W2, W3, Ah, Al, W1Th, W1Tl, W2Th, W2Tl, W3Th, W3Tl);

  // layer 1
  k_gemm<<<gemm_grid, 256, 0, stream>>>(Ah, Al, W1Th, W1Tl, b1, uv, 64);
  k_edge<64><<<NG, 256, 0, stream>>>(Ah, Al, uv, hA, part);
  k_stats<<<HID, 256, 0, stream>>>(part, g1, be1, st1);

  // layer 2
  k_bnrelu<<<NROWS * HID / 1024, 256, 0, stream>>>(hA, st1, Ah, Al);
  k_gemm<<<gemm_grid, 256, 0, stream>>>(Ah, Al, W2Th, W2Tl, b2, uv, 256);
  k_edge<256><<<NG, 256, 0, stream>>>(Ah, Al, uv, hB, part);
  k_stats<<<HID, 256, 0, stream>>>(part, g2, be2, st2);

  // layer 3
  k_bnrelu<<<NROWS * HID / 1024, 256, 0, stream>>>(hB, st2, Ah, Al);
  k_gemm<<<gemm_grid, 256, 0, stream>>>(Ah, Al, W3Th, W3Tl, b3, uv, 256);
  k_edge<256><<<NG, 256, 0, stream>>>(Ah, Al, uv, hA, part);
  k_stats<<<HID, 256, 0, stream>>>(part, g3, be3, st3);

  // pool + linear + softmax
  k_final<<<NG, 256, 0, stream>>>(hA, st3, Wl, bl, (float*)d_out);
}

// Round 4
// 159.068 us; speedup vs baseline: 2.2344x; 1.0718x over previous
//
#include <hip/hip_runtime.h>
#include <hip/hip_bf16.h>
#include <stdint.h>

#define NG 512            // graphs
#define NN 39             // nodes per graph
#define FIN0 39           // input features
#define HID 256
#define KNN 10
#define NROWS (NG * NN)   // 19968
#define BNEPS 1e-5f

typedef __hip_bfloat16 bf16;
typedef __attribute__((ext_vector_type(8))) short s16x8;
typedef __attribute__((ext_vector_type(4))) float f32x4;

__device__ __forceinline__ void gld_lds16(const void* g, void* l) {
  __builtin_amdgcn_global_load_lds(
      (const __attribute__((address_space(1))) void*)(uintptr_t)g,
      (__attribute__((address_space(3))) void*)(uintptr_t)l, 16, 0, 0);
}

__device__ __forceinline__ void split_bf16(float v, bf16& hi, bf16& lo) {
  hi = __float2bfloat16(v);
  lo = __float2bfloat16(v - __bfloat162float(hi));
}

// ---------------------------------------------------------------------------
// prep: A1 = split-bf16(x) zero-padded to K=64; W*T = folded+transposed
// split-bf16 weights. WT layout [512 outcols][K]: col<256 -> W_top - W_bot
// (u-half), col>=256 -> W_bot (v-half). 4 elems/thread, packed u64 stores.
// ---------------------------------------------------------------------------
__global__ void k_prep(const float* __restrict__ x, const float* __restrict__ W1,
                       const float* __restrict__ W2, const float* __restrict__ W3,
                       bf16* __restrict__ A1h, bf16* __restrict__ A1l,
                       bf16* __restrict__ W1Th, bf16* __restrict__ W1Tl,
                       bf16* __restrict__ W2Th, bf16* __restrict__ W2Tl,
                       bf16* __restrict__ W3Th, bf16* __restrict__ W3Tl) {
  const int i = (blockIdx.x * 256 + threadIdx.x) * 4;
  const int nA1 = NROWS * 64;
  union U { bf16 b[4]; uint64_t u; };
  U h, l;
  if (i < nA1) {
    const int r = i >> 6, k = i & 63;
#pragma unroll
    for (int t = 0; t < 4; t++) {
      const float v = (k + t < FIN0) ? x[r * FIN0 + k + t] : 0.f;
      split_bf16(v, h.b[t], l.b[t]);
    }
    *(uint64_t*)(A1h + i) = h.u; *(uint64_t*)(A1l + i) = l.u;
    return;
  }
  int j = i - nA1;                       // W1T: [512][64]
  if (j < 512 * 64) {
    const int c = j >> 6, k = j & 63;
#pragma unroll
    for (int t = 0; t < 4; t++) {
      float v = 0.f;
      if (k + t < FIN0)
        v = (c < HID) ? (W1[(k + t) * HID + c] - W1[(FIN0 + k + t) * HID + c])
                      : W1[(FIN0 + k + t) * HID + (c - HID)];
      split_bf16(v, h.b[t], l.b[t]);
    }
    *(uint64_t*)(W1Th + j) = h.u; *(uint64_t*)(W1Tl + j) = l.u;
    return;
  }
  j -= 512 * 64;                         // W2T: [512][256]
  if (j < 512 * 256) {
    const int c = j >> 8, k = j & 255;
#pragma unroll
    for (int t = 0; t < 4; t++) {
      const float v = (c < HID) ? (W2[(k + t) * HID + c] - W2[(HID + k + t) * HID + c])
                                : (W2[(HID + k + t) * HID + (c - HID)]);
      split_bf16(v, h.b[t], l.b[t]);
    }
    *(uint64_t*)(W2Th + j) = h.u; *(uint64_t*)(W2Tl + j) = l.u;
    return;
  }
  j -= 512 * 256;                        // W3T: [512][256]
  if (j < 512 * 256) {
    const int c = j >> 8, k = j & 255;
#pragma unroll
    for (int t = 0; t < 4; t++) {
      const float v = (c < HID) ? (W3[(k + t) * HID + c] - W3[(HID + k + t) * HID + c])
                                : (W3[(HID + k + t) * HID + (c - HID)]);
      split_bf16(v, h.b[t], l.b[t]);
    }
    *(uint64_t*)(W3Th + j) = h.u; *(uint64_t*)(W3Tl + j) = l.u;
  }
}

// ---------------------------------------------------------------------------
// Fused layer kernel: one block (512 thr, 8 waves) per graph.
//  p0: stage split-bf16 X rows -> LDS (swizzled src, linear dest), pad rows 0
//  p1: Gram via MFMA (3-product split)  -> dmat;  d_ii == 0 exactly
//  p2: distances in place; p3: 4-lane-group top-10 (stable tie-break)
//  p4: GEMM u|v = X @ WT^T: wave w owns cols w*64..w*64+63.
//      waves 0-3: u + bias kept in acc regs; waves 4-7: v -> vsh (aliases X)
//  p5: h = relu(u + max_k vsh[idx]); write h_out; per-graph BN partials.
// LDS ~57KB -> 2 blocks/CU (16 waves).
// ---------------------------------------------------------------------------
template <int K>   // 64 (layer1) or 256 (layers 2/3)
__global__ __launch_bounds__(512, 4) void k_fused(const bf16* __restrict__ Ah,
                                                  const bf16* __restrict__ Al,
                                                  const bf16* __restrict__ BTh,
                                                  const bf16* __restrict__ BTl,
                                                  const float* __restrict__ bias,
                                                  float* __restrict__ h_out,
                                                  float* __restrict__ part) {
  constexpr int GPR = K / 8;                        // 16B granules per row
  constexpr int XBYTES = 48 * K * 2 * 2;            // Xh+Xl
  constexpr int SBASE = (XBYTES > 48128) ? XBYTES : 48128;  // {vsh,red} alias X
  __shared__ __align__(16) char smem[SBASE + 6240 + 160 + 1568];
  bf16* Xh = (bf16*)smem;                  // [48][K]
  bf16* Xl = Xh + 48 * K;                  // [48][K]
  float* vsh = (float*)smem;               // [39][256]  (phase>=4, X dead)
  float* red = (float*)(smem + 39936);     // [8][256]   (phase 5)
  float* dmat = (float*)(smem + SBASE);    // [39][40]
  float* sqv  = (float*)(smem + SBASE + 6240);      // [39]
  int*   idxs = (int*)(smem + SBASE + 6240 + 160);  // [39][10]

  const int b = blockIdx.x, tid = threadIdx.x;
  const int wv = tid >> 6, ln = tid & 63;
  const int fr = ln & 15, fq = ln >> 4;
  const size_t base = (size_t)b * NN;

  // ---- p0: stage X (pre-swizzled source, linear LDS dest) ----
  for (int t0 = 0; t0 < 48 * GPR; t0 += 512) {
    const int t = t0 + tid;
    if (t < 48 * GPR) {
      const int row = t / GPR, g = t % GPR;
      bf16* dh = Xh + (size_t)(t0 + wv * 64) * 8;   // wave-uniform base
      bf16* dl = Xl + (size_t)(t0 + wv * 64) * 8;
      if (row < NN) {
        const size_t src = (size_t)(base + row) * K + ((g ^ (row & 7)) << 3);
        gld_lds16(Ah + src, dh);
        gld_lds16(Al + src, dl);
      } else {
        *(f32x4*)(Xh + (size_t)t * 8) = (f32x4){0.f, 0.f, 0.f, 0.f};
        *(f32x4*)(Xl + (size_t)t * 8) = (f32x4){0.f, 0.f, 0.f, 0.f};
      }
    }
  }
  __syncthreads();

  // ---- p1: Gram via MFMA (9 16x16 tile-pairs over 8 waves) ----
  for (int p = wv; p < 9; p += 8) {
    const int mi = p / 3, ni = p % 3;
    f32x4 acc = (f32x4){0.f, 0.f, 0.f, 0.f};
    const int ar = mi * 16 + fr, br = ni * 16 + fr;
#pragma unroll
    for (int ks = 0; ks < K / 32; ks++) {
      const int ga = ((ks * 4 + fq) ^ (ar & 7)) << 3;
      const int gb = ((ks * 4 + fq) ^ (br & 7)) << 3;
      const s16x8 avh = *(const s16x8*)&Xh[ar * K + ga];
      const s16x8 avl = *(const s16x8*)&Xl[ar * K + ga];
      const s16x8 bvh = *(const s16x8*)&Xh[br * K + gb];
      const s16x8 bvl = *(const s16x8*)&Xl[br * K + gb];
      acc = __builtin_amdgcn_mfma_f32_16x16x32_bf16(avh, bvh, acc, 0, 0, 0);
      acc = __builtin_amdgcn_mfma_f32_16x16x32_bf16(avh, bvl, acc, 0, 0, 0);
      acc = __builtin_amdgcn_mfma_f32_16x16x32_bf16(avl, bvh, acc, 0, 0, 0);
    }
    const int oc = ni * 16 + fr;           // C layout: col=lane&15
    if (oc < NN) {
#pragma unroll
      for (int r = 0; r < 4; r++) {        // row=(lane>>4)*4+reg
        const int orow = mi * 16 + fq * 4 + r;
        if (orow < NN) dmat[orow * 40 + oc] = acc[r];
      }
    }
  }
  __syncthreads();

  // ---- p2: distances in place ----
  if (tid < NN) sqv[tid] = dmat[tid * 40 + tid];
  __syncthreads();
  for (int t = tid; t < NN * NN; t += 512) {
    const int i = t / NN, j = t - i * NN;
    dmat[i * 40 + j] = sqv[i] + sqv[j] - 2.f * dmat[i * 40 + j];
  }
  __syncthreads();

  // ---- p3: top-10 per row, 4-lane groups (stable tie-break = lax.top_k) ----
  const int grp = tid >> 2, l4 = tid & 3;
  if (grp < NN) {
    float dv[10];
#pragma unroll
    for (int s = 0; s < 10; s++) {
      const int j = l4 + s * 4;
      dv[s] = (j < NN) ? dmat[grp * 40 + j] : 3.4e38f;
    }
    unsigned taken = 0;
    for (int k = 0; k < KNN; k++) {
      float bv = 3.4e38f;
      int bi = 1 << 30;
#pragma unroll
      for (int s = 0; s < 10; s++) {
        const float v = ((taken >> s) & 1u) ? 3.4e38f : dv[s];
        const int j = l4 + s * 4;
        if (v < bv || (v == bv && j < bi)) { bv = v; bi = j; }
      }
#pragma unroll
      for (int m = 1; m < 4; m <<= 1) {
        const float ov = __shfl_xor(bv, m, 64);
        const int oi = __shfl_xor(bi, m, 64);
        if (ov < bv || (ov == bv && oi < bi)) { bv = ov; bi = oi; }
      }
      if ((bi & 3) == l4) taken |= 1u << (bi >> 2);
      if (l4 == 0) idxs[grp * 10 + k] = bi;
    }
  }

  // ---- p4: GEMM. wave wv owns output cols [wv*64, wv*64+64) ----
  const int wcol0 = wv * 64;
  f32x4 acc[3][4];
#pragma unroll
  for (int m = 0; m < 3; m++)
#pragma unroll
    for (int n = 0; n < 4; n++) acc[m][n] = (f32x4){0.f, 0.f, 0.f, 0.f};
#pragma unroll 2
  for (int ks = 0; ks < K / 32; ks++) {
    s16x8 avh[3], avl[3], bvh[4], bvl[4];
#pragma unroll
    for (int m = 0; m < 3; m++) {
      const int row = m * 16 + fr;
      const int g = ((ks * 4 + fq) ^ (row & 7)) << 3;
      avh[m] = *(const s16x8*)&Xh[row * K + g];
      avl[m] = *(const s16x8*)&Xl[row * K + g];
    }
#pragma unroll
    for (int n = 0; n < 4; n++) {
      const size_t bo = (size_t)(wcol0 + n * 16 + fr) * K + ks * 32 + fq * 8;
      bvh[n] = *(const s16x8*)(BTh + bo);
      bvl[n] = *(const s16x8*)(BTl + bo);
    }
#pragma unroll
    for (int m = 0; m < 3; m++)
#pragma unroll
      for (int n = 0; n < 4; n++) {
        acc[m][n] = __builtin_amdgcn_mfma_f32_16x16x32_bf16(avh[m], bvh[n], acc[m][n], 0, 0, 0);
        acc[m][n] = __builtin_amdgcn_mfma_f32_16x16x32_bf16(avh[m], bvl[n], acc[m][n], 0, 0, 0);
        acc[m][n] = __builtin_amdgcn_mfma_f32_16x16x32_bf16(avl[m], bvh[n], acc[m][n], 0, 0, 0);
      }
  }
  __syncthreads();   // all A-reads done; X region may be overwritten (vsh)

  if (wv >= 4) {     // v-waves: acc -> vsh[row][c], c = col-256
#pragma unroll
    for (int m = 0; m < 3; m++)
#pragma unroll
      for (int n = 0; n < 4; n++) {
        const int c = wcol0 - 256 + n * 16 + fr;
#pragma unroll
        for (int r = 0; r < 4; r++) {
          const int row = m * 16 + fq * 4 + r;
          if (row < NN) vsh[row * 256 + c] = acc[m][n][r];
        }
      }
  } else {           // u-waves: add bias
#pragma unroll
    for (int n = 0; n < 4; n++) {
      const float bb = bias[wcol0 + n * 16 + fr];
#pragma unroll
      for (int m = 0; m < 3; m++)
#pragma unroll
        for (int r = 0; r < 4; r++) acc[m][n][r] += bb;
    }
  }
  __syncthreads();   // vsh + idxs ready

  // ---- p5: h = relu(u + max_k v); BN partials (u-waves only) ----
  if (wv < 4) {
    f32x4 s1 = (f32x4){0.f, 0.f, 0.f, 0.f}, s2 = (f32x4){0.f, 0.f, 0.f, 0.f};
#pragma unroll
    for (int m = 0; m < 3; m++)
#pragma unroll
      for (int r = 0; r < 4; r++) {
        const int row = m * 16 + fq * 4 + r;
        if (row < NN) {
          int nb[10];
#pragma unroll
          for (int k = 0; k < KNN; k++) nb[k] = idxs[row * 10 + k];
#pragma unroll
          for (int n = 0; n < 4; n++) {
            const int c = wcol0 + n * 16 + fr;
            float vm = -3.4e38f;
#pragma unroll
            for (int k = 0; k < KNN; k++) vm = fmaxf(vm, vsh[nb[k] * 256 + c]);
            const float h = fmaxf(acc[m][n][r] + vm, 0.f);
            h_out[(size_t)(base + row) * HID + c] = h;
            s1[n] += h; s2[n] += h * h;
          }
        }
      }
#pragma unroll
    for (int n = 0; n < 4; n++) {
      const int c = wcol0 + n * 16 + fr;
      red[fq * 256 + c] = s1[n];
      red[(4 + fq) * 256 + c] = s2[n];
    }
  }
  __syncthreads();
  if (tid < HID) {
    part[(size_t)b * 512 + tid] =
        red[0 * 256 + tid] + red[1 * 256 + tid] + red[2 * 256 + tid] + red[3 * 256 + tid];
    part[(size_t)b * 512 + HID + tid] =
        red[4 * 256 + tid] + red[5 * 256 + tid] + red[6 * 256 + tid] + red[7 * 256 + tid];
  }
}

// stats reduce: one block per channel; deterministic tree order.
__global__ __launch_bounds__(256) void k_stats(const float* __restrict__ part,
                                               const float* __restrict__ gam,
                                               const float* __restrict__ bet,
                                               float* __restrict__ st) {
  __shared__ float rs[4], rq[4];
  const int c = blockIdx.x, tid = threadIdx.x;
  float s = part[(size_t)tid * 512 + c] + part[(size_t)(tid + 256) * 512 + c];
  float q = part[(size_t)tid * 512 + HID + c] + part[(size_t)(tid + 256) * 512 + HID + c];
#pragma unroll
  for (int m = 32; m >= 1; m >>= 1) { s += __shfl_down(s, m, 64); q += __shfl_down(q, m, 64); }
  if ((tid & 63) == 0) { rs[tid >> 6] = s; rq[tid >> 6] = q; }
  __syncthreads();
  if (tid == 0) {
    s = rs[0] + rs[1] + rs[2] + rs[3];
    q = rq[0] + rq[1] + rq[2] + rq[3];
    const float mean = s * (1.f / NROWS);
    const float var = q * (1.f / NROWS) - mean * mean;
    const float sc = gam[c] * rsqrtf(var + BNEPS);
    st[c] = sc;
    st[HID + c] = bet[c] - mean * sc;
  }
}

// A = split-bf16(relu(h*sc+sh))  (next layer's GEMM + kNN input)
__global__ void k_bnrelu(const float* __restrict__ h, const float* __restrict__ st,
                         bf16* __restrict__ Ah, bf16* __restrict__ Al) {
  const size_t e = ((size_t)blockIdx.x * 256 + threadIdx.x) * 4;
  const int c = (int)(e & 255);
  const f32x4 v = *(const f32x4*)(h + e);
  union { bf16 b[4]; uint64_t u; } ph, pl;
#pragma unroll
  for (int t = 0; t < 4; t++) {
    const float r = fmaxf(v[t] * st[c + t] + st[HID + c + t], 0.f);
    split_bf16(r, ph.b[t], pl.b[t]);
  }
  *(uint64_t*)(Ah + e) = ph.u;
  *(uint64_t*)(Al + e) = pl.u;
}

// pooled = BN(mean_n h3) (affine commutes with mean; no relu); logits; softmax
__global__ __launch_bounds__(256) void k_final(const float* __restrict__ h3,
                                               const float* __restrict__ st,
                                               const float* __restrict__ Wl,
                                               const float* __restrict__ bl,
                                               float* __restrict__ out) {
  __shared__ float r0[HID], r1[HID];
  const int b = blockIdx.x, c = threadIdx.x;
  float s = 0.f;
  for (int n = 0; n < NN; n++) s += h3[((size_t)b * NN + n) * HID + c];
  const float pooled = (s * (1.f / NN)) * st[c] + st[HID + c];
  r0[c] = pooled * Wl[c * 2 + 0];
  r1[c] = pooled * Wl[c * 2 + 1];
  __syncthreads();
  for (int stp = 128; stp > 0; stp >>= 1) {
    if (c < stp) { r0[c] += r0[c + stp]; r1[c] += r1[c + stp]; }
    __syncthreads();
  }
  if (c == 0) {
    const float l0 = r0[0] + bl[0], l1 = r1[0] + bl[1];
    const float mx = fmaxf(l0, l1);
    const float e0 = expf(l0 - mx), e1 = expf(l1 - mx);
    const float inv = 1.f / (e0 + e1);
    out[b * 2 + 0] = e0 * inv;
    out[b * 2 + 1] = e1 * inv;
  }
}

extern "C" void kernel_launch(void* const* d_in, const int* in_sizes, int n_in,
                              void* d_out, int out_size, void* d_ws, size_t ws_size,
                              hipStream_t stream) {
  const float* x   = (const float*)d_in[0];
  // d_in[1] = batch (structure fixed: repeat(arange(512), 39)) -- unused
  const float* W1  = (const float*)d_in[2];
  const float* b1  = (const float*)d_in[3];
  const float* W2  = (const float*)d_in[4];
  const float* b2  = (const float*)d_in[5];
  const float* W3  = (const float*)d_in[6];
  const float* b3  = (const float*)d_in[7];
  const float* g1  = (const float*)d_in[8];
  const float* be1 = (const float*)d_in[9];
  const float* g2  = (const float*)d_in[10];
  const float* be2 = (const float*)d_in[11];
  const float* g3  = (const float*)d_in[12];
  const float* be3 = (const float*)d_in[13];
  const float* Wl  = (const float*)d_in[14];
  const float* bl  = (const float*)d_in[15];

  char* ws = (char*)d_ws;
  size_t off = 0;
  auto alloc = [&](size_t bytes) {
    size_t o = off;
    off += (bytes + 255) & ~(size_t)255;
    return o;
  };
  bf16* Ah   = (bf16*)(ws + alloc((size_t)NROWS * HID * 2));   // split features hi (layer1: [.][64] prefix)
  bf16* Al   = (bf16*)(ws + alloc((size_t)NROWS * HID * 2));   // split features lo
  bf16* W1Th = (bf16*)(ws + alloc(512 * 64 * 2));
  bf16* W1Tl = (bf16*)(ws + alloc(512 * 64 * 2));
  bf16* W2Th = (bf16*)(ws + alloc(512 * 256 * 2));
  bf16* W2Tl = (bf16*)(ws + alloc(512 * 256 * 2));
  bf16* W3Th = (bf16*)(ws + alloc(512 * 256 * 2));
  bf16* W3Tl = (bf16*)(ws + alloc(512 * 256 * 2));
  float* hA  = (float*)(ws + alloc((size_t)NROWS * HID * 4));
  float* hB  = (float*)(ws + alloc((size_t)NROWS * HID * 4));
  float* part = (float*)(ws + alloc((size_t)NG * 512 * 4));
  float* st1 = (float*)(ws + alloc(512 * 4));
  float* st2 = (float*)(ws + alloc(512 * 4));
  float* st3 = (float*)(ws + alloc(512 * 4));
  if (off > ws_size) return;  // workspace too small -> visible failure

  k_prep<<<1536, 256, 0, stream>>>(x, W1, W2, W3, Ah, Al, W1Th, W1Tl, W2Th, W2Tl, W3Th, W3Tl);

  // layer 1
  k_fused<64><<<NG, 512, 0, stream>>>(Ah, Al, W1Th, W1Tl, b1, hA, part);
  k_stats<<<HID, 256, 0, stream>>>(part, g1, be1, st1);

  // layer 2
  k_bnrelu<<<NROWS * HID / 1024, 256, 0, stream>>>(hA, st1, Ah, Al);
  k_fused<256><<<NG, 512, 0, stream>>>(Ah, Al, W2Th, W2Tl, b2, hB, part);
  k_stats<<<HID, 256, 0, stream>>>(part, g2, be2, st2);

  // layer 3
  k_bnrelu<<<NROWS * HID / 1024, 256, 0, stream>>>(hB, st2, Ah, Al);
  k_fused<256><<<NG, 512, 0, stream>>>(Ah, Al, W3Th, W3Tl, b3, hA, part);
  k_stats<<<HID, 256, 0, stream>>>(part, g3, be3, st3);

  // pool + linear + softmax
  k_final<<<NG, 256, 0, stream>>>(hA, st3, Wl, bl, (float*)d_out);
}